// Round 17
// baseline (572.612 us; speedup 1.0000x reference)
//
#include <hip/hip_runtime.h>
#include <hip/hip_bf16.h>
#include <math.h>

typedef float f32x4 __attribute__((ext_vector_type(4)));
typedef __bf16 bf16x8 __attribute__((ext_vector_type(8)));

#define NTOK 98
#define NWIN 2048
#define NN (NTOK * NTOK)            // 9604
#define SCALE 0.17677669529663689f
#define MROWS (NWIN * NTOK)         // 200704
#define PSTRIDE 9408                // per-(win,h): q 3136 + k 3136 + v 3136 elems

// ---------------- async global->LDS 16B ----------------
__device__ __forceinline__ void g2l16(const void* g, void* l) {
  typedef __attribute__((address_space(1))) const unsigned int GU;
  typedef __attribute__((address_space(3))) unsigned int LU;
  __builtin_amdgcn_global_load_lds((GU*)g, (LU*)l, 16, 0, 0);
}

// ---------------- prep: weights->bf16, cmb[m][h][98][128] = bias+mask (fp32) ----------------
__global__ void prep_kernel(const float* __restrict__ qkv_w, const float* __restrict__ proj_w,
                            const float* __restrict__ pbt, const int* __restrict__ rpi,
                            const float* __restrict__ mask,
                            __bf16* __restrict__ qkvw_b, __bf16* __restrict__ projw_b,
                            float* __restrict__ cmb) {
  int i = blockIdx.x * 256 + threadIdx.x;
  if (i < 768 * 256) qkvw_b[i] = (__bf16)qkv_w[i];
  if (i < 256 * 256) projw_b[i] = (__bf16)proj_w[i];
  if (i < 256 * 8 * NTOK * 128) {
    int mh = i / (NTOK * 128);            // m*8 + h
    int rem = i - mh * (NTOK * 128);
    int row = rem >> 7, j = rem & 127;
    if (j < NTOK) {
      int m = mh >> 3, h = mh & 7;
      cmb[i] = pbt[rpi[row * NTOK + j] * 8 + h] + mask[m * NN + row * NTOK + j];
    } else {
      cmb[i] = 0.f;
    }
  }
}

// ---------------- QKV GEMM: A once, B dbuf BK=32, 512 thr (8 waves, 2M x 4N) ----------------
__launch_bounds__(512)
__global__ void gemm_qkv(const float* __restrict__ A, const __bf16* __restrict__ W,
                         __bf16* __restrict__ C) {
  __shared__ __align__(16) char As[65536];       // [128 rows][256 bf16] swizzled
  __shared__ __align__(16) char Bs[2][8192];     // [128 rows][32 bf16] swizzled, dbuf
  const int m0 = blockIdx.x * 128;
  const int tid = threadIdx.x;
  const int lane = tid & 63;
  const int wid = tid >> 6;                      // 0..7
  const int wm = wid >> 2, wn = wid & 3;         // 2M x 4N, 64x32 per wave
  const int lr = lane & 15;
  const int lg = lane >> 4;

  // stage A once: fp32 -> bf16 through regs, swizzled, K fully resident
  for (int c = tid; c < 128 * 32; c += 512) {
    int row = c >> 5, slot = c & 31;
    const float* ap = A + (size_t)(m0 + row) * 256 + slot * 8;
    float4 f0 = *(const float4*)ap;
    float4 f1 = *(const float4*)(ap + 4);
    bf16x8 hv;
    hv[0] = (__bf16)f0.x; hv[1] = (__bf16)f0.y; hv[2] = (__bf16)f0.z; hv[3] = (__bf16)f0.w;
    hv[4] = (__bf16)f1.x; hv[5] = (__bf16)f1.y; hv[6] = (__bf16)f1.z; hv[7] = (__bf16)f1.w;
    *(bf16x8*)(As + row * 512 + ((slot * 16) ^ ((row & 7) << 4))) = hv;
  }
  __syncthreads();

  for (int nt = 0; nt < 6; ++nt) {
    const int n0 = nt * 128;
    f32x4 acc[4][2] = {};

    // stage B k-step 0 into buf 0 (pre-swizzled source, linear dest); 1 chunk-group/wave
    {
      int cc = wid * 64 + lane;               // 16B chunk id 0..511
      int row = cc >> 2, slot = cc & 3;
      int sw = (row & 3) ^ ((row >> 3) & 3);
      g2l16(W + (size_t)(n0 + row) * 256 + ((slot ^ sw) * 8), (void*)(Bs[0] + wid * 1024));
    }
    __syncthreads();

    for (int ks = 0; ks < 8; ++ks) {
      const int cur = ks & 1;
      if (ks < 7) {
        int cc = wid * 64 + lane;
        int row = cc >> 2, slot = cc & 3;
        int sw = (row & 3) ^ ((row >> 3) & 3);
        g2l16(W + (size_t)(n0 + row) * 256 + (ks + 1) * 32 + ((slot ^ sw) * 8),
              (void*)(Bs[cur ^ 1] + wid * 1024));
      }
      bf16x8 a[4], b[2];
#pragma unroll
      for (int m = 0; m < 4; ++m) {
        int row = wm * 64 + m * 16 + lr;
        a[m] = *(const bf16x8*)(As + row * 512 + ((ks * 64 + lg * 16) ^ ((row & 7) << 4)));
      }
#pragma unroll
      for (int n = 0; n < 2; ++n) {
        int row = wn * 32 + n * 16 + lr;
        int sw = (row & 3) ^ ((row >> 3) & 3);
        b[n] = *(const bf16x8*)(Bs[cur] + row * 64 + ((lg * 16) ^ (sw << 4)));
      }
#pragma unroll
      for (int m = 0; m < 4; ++m)
#pragma unroll
        for (int n = 0; n < 2; ++n)
          acc[m][n] = __builtin_amdgcn_mfma_f32_16x16x32_bf16(a[m], b[n], acc[m][n], 0, 0, 0);
      __syncthreads();   // stage(ks+1) landed; reads of Bs[cur] done
    }

    // epilogue for this nt: head-blocked, linear [tok][32] -> coalesced 32B stores
#pragma unroll
    for (int m = 0; m < 4; ++m)
#pragma unroll
      for (int r = 0; r < 4; ++r) {
        unsigned row = m0 + wm * 64 + m * 16 + lg * 4 + r;
        unsigned win = row / NTOK;
        unsigned tok = row - win * NTOK;
#pragma unroll
        for (int n = 0; n < 2; ++n) {
          int col = n0 + wn * 32 + n * 16 + lr;
          int sec = col >> 8, dd = col & 255;
          int h = dd >> 5, d = dd & 31;
          C[(size_t)(win * 8 + h) * PSTRIDE + (size_t)sec * 3136 + tok * 32 + d] =
              (__bf16)acc[m][n][r];
        }
      }
  }
}

// ---------------- attention: VT staged in LDS; hoisted K frags; 2 waves ----------------
__launch_bounds__(128)
__global__ void attn_kernel(const __bf16* __restrict__ qkv, const float* __restrict__ cmb,
                            __bf16* __restrict__ y) {
  __shared__ __align__(16) char VTB[8192];      // VT [32 d][128 j] bf16, swizzled
  int bx = blockIdx.x;
  int lb = (bx & 7) * 2048 + (bx >> 3);         // win-major within each XCD
  const int win = lb >> 3, h = lb & 7;
  const int tid = threadIdx.x;
  const int lane = tid & 63, wv = tid >> 6;
  const int lr = lane & 15, lg = lane >> 4;
  const f32x4 fz = {0.f, 0.f, 0.f, 0.f};

  const __bf16* qw = qkv + (size_t)(win * 8 + h) * PSTRIDE;
  const __bf16* kw = qw + 3136;
  const __bf16* vw = qw + 6272;                 // v [tok][32]
  const float* cw = cmb + (size_t)((win & 255) * 8 + h) * (NTOK * 128);

  // stage V transposed -> VT (clamped rows j>=98; they multiply P=0)
  for (int c = tid; c < 512; c += 128) {
    int j = c & 127; int jc = j < NTOK ? j : NTOK - 1;
    int d8 = (c >> 7) << 3;
    bf16x8 vv = *(const bf16x8*)(vw + jc * 32 + d8);
#pragma unroll
    for (int e = 0; e < 8; ++e) {
      int d = d8 + e;
      *(__bf16*)(VTB + d * 256 + ((2 * j) ^ ((d & 7) << 4))) = vv[e];
    }
  }

  // hoist K fragments (i-tile-invariant), permuted so P slots == PV A-frag slots
  bf16x8 bk[7];
#pragma unroll
  for (int jt = 0; jt < 7; ++jt) {
    int brow = ((jt >> 1) << 5) + ((lr >> 2) << 3) + ((jt & 1) << 2) + (lr & 3);
    int browc = brow < NTOK ? brow : NTOK - 1;
    bk[jt] = *(const bf16x8*)(kw + browc * 32 + lg * 8);
  }
  __syncthreads();

  for (int it = wv; it < 7; it += 2) {          // wave0: 0,2,4,6  wave1: 1,3,5
    const int i0 = it * 16;
    const int qrow = i0 + lr;
    const int qrowc = qrow < NTOK ? qrow : NTOK - 1;
    bf16x8 aq = *(const bf16x8*)(qw + qrowc * 32 + lg * 8);

    // prefetch combined bias+mask (hides under QK^T)
    const float* cr = cw + qrowc * 128;
    float4 cv[7];
#pragma unroll
    for (int jt = 0; jt < 7; ++jt) {
      int kb = ((jt >> 1) << 5) + lg * 8 + ((jt & 1) << 2);
      cv[jt] = *(const float4*)(cr + kb);
    }

    // S^T = K Q^T: lane holds P[qrow][k], k = 32*(jt>>1) + lg*8 + 4*(jt&1) + r
    f32x4 s[7];
#pragma unroll
    for (int jt = 0; jt < 7; ++jt)
      s[jt] = __builtin_amdgcn_mfma_f32_16x16x32_bf16(bk[jt], aq, fz, 0, 0, 0);

    // softmax fully in-register (row qrow)
    float sv[7][4];
    float mx = -INFINITY;
#pragma unroll
    for (int jt = 0; jt < 7; ++jt) {
      int kb = ((jt >> 1) << 5) + lg * 8 + ((jt & 1) << 2);
#pragma unroll
      for (int r = 0; r < 4; ++r) {
        float xv = (kb + r < NTOK) ? fmaf(SCALE, s[jt][r], (&cv[jt].x)[r]) : -INFINITY;
        sv[jt][r] = xv;
        mx = fmaxf(mx, xv);
      }
    }
    mx = fmaxf(mx, __shfl_xor(mx, 16));
    mx = fmaxf(mx, __shfl_xor(mx, 32));
    float sum = 0.f;
#pragma unroll
    for (int jt = 0; jt < 7; ++jt)
#pragma unroll
      for (int r = 0; r < 4; ++r) {
        float p = __expf(sv[jt][r] - mx);
        sv[jt][r] = p;
        sum += p;
      }
    sum += __shfl_xor(sum, 16);
    sum += __shfl_xor(sum, 32);
    const float rinv = 1.f / sum;               // for row i0 + lr

    // PV A-frags (unnormalized); jt==7 phantom slots -> 0
    bf16x8 pa[4];
#pragma unroll
    for (int ks = 0; ks < 4; ++ks)
#pragma unroll
      for (int e = 0; e < 8; ++e) {
        int jt = 2 * ks + (e >> 2);
        pa[ks][e] = (jt < 7) ? (__bf16)sv[jt][e & 3] : (__bf16)0.f;
      }

    // output row of o[r] is i0+lg*4+r -> reciprocal from lane lg*4+r
    float rv[4];
#pragma unroll
    for (int r = 0; r < 4; ++r) rv[r] = __shfl(rinv, lg * 4 + r);

    // PV from LDS V^T; y write with row-correct reciprocal
#pragma unroll
    for (int dt = 0; dt < 2; ++dt) {
      f32x4 o = fz;
#pragma unroll
      for (int ks = 0; ks < 4; ++ks) {
        int vrow = dt * 16 + lr;
        bf16x8 vb = *(const bf16x8*)(VTB + vrow * 256 + ((ks * 64 + lg * 16) ^ ((vrow & 7) << 4)));
        o = __builtin_amdgcn_mfma_f32_16x16x32_bf16(pa[ks], vb, o, 0, 0, 0);
      }
#pragma unroll
      for (int r = 0; r < 4; ++r) {
        int row = i0 + lg * 4 + r;
        if (row < NTOK)
          y[((size_t)win * NTOK + row) * 256 + h * 32 + dt * 16 + lr] = (__bf16)(o[r] * rv[r]);
      }
    }
  }
}

// ---------------- proj GEMM: out[M][256] = y[M][256] @ W[256][256]^T + b ----------------
__launch_bounds__(256)
__global__ void gemm_proj(const __bf16* __restrict__ A, const __bf16* __restrict__ W,
                          const float* __restrict__ pb, float* __restrict__ C) {
  __shared__ __align__(16) char As[128 * 128];
  __shared__ __align__(16) char Bs[128 * 128];
  const int bid = blockIdx.x;
  const int m0 = (bid / 2) * 128;
  const int n0 = (bid % 2) * 128;
  const int tid = threadIdx.x;
  const int lane = tid & 63;
  const int wid = tid >> 6;
  const int wm = wid & 1, wn = wid >> 1;
  const int lr = lane & 15;
  const int lg = lane >> 4;
  f32x4 acc[4][4] = {};

  for (int k0 = 0; k0 < 256; k0 += 64) {
#pragma unroll
    for (int it = 0; it < 4; ++it) {
      int c = wid * 4 + it;
      int row = c * 8 + (lane >> 3);
      int src_chunk = (lane & 7) ^ (row & 7);
      g2l16(A + (size_t)(m0 + row) * 256 + k0 + src_chunk * 8, (void*)(As + c * 1024));
      g2l16(W + (size_t)(n0 + row) * 256 + k0 + src_chunk * 8, (void*)(Bs + c * 1024));
    }
    __syncthreads();
#pragma unroll
    for (int kk = 0; kk < 2; ++kk) {
      bf16x8 a[4], b[4];
#pragma unroll
      for (int m = 0; m < 4; ++m) {
        int row = wm * 64 + m * 16 + lr;
        a[m] = *(const bf16x8*)(As + row * 128 + ((kk * 64 + lg * 16) ^ ((row & 7) << 4)));
      }
#pragma unroll
      for (int n = 0; n < 4; ++n) {
        int row = wn * 64 + n * 16 + lr;
        b[n] = *(const bf16x8*)(Bs + row * 128 + ((kk * 64 + lg * 16) ^ ((row & 7) << 4)));
      }
#pragma unroll
      for (int m = 0; m < 4; ++m)
#pragma unroll
        for (int n = 0; n < 4; ++n)
          acc[m][n] = __builtin_amdgcn_mfma_f32_16x16x32_bf16(a[m], b[n], acc[m][n], 0, 0, 0);
    }
    __syncthreads();
  }
#pragma unroll
  for (int m = 0; m < 4; ++m) {
    int row = m0 + wm * 64 + m * 16 + lg * 4;
#pragma unroll
    for (int n = 0; n < 4; ++n) {
      int col = n0 + wn * 64 + n * 16 + lr;
      float bv = pb[col];
#pragma unroll
      for (int r = 0; r < 4; ++r)
        C[(size_t)(row + r) * 256 + col] = acc[m][n][r] + bv;
    }
  }
}

// ---------------- launch ----------------
extern "C" void kernel_launch(void* const* d_in, const int* in_sizes, int n_in,
                              void* d_out, int out_size, void* d_ws, size_t ws_size,
                              hipStream_t stream) {
  const float* x      = (const float*)d_in[0];
  const float* mask   = (const float*)d_in[1];
  const float* pbt    = (const float*)d_in[2];
  const float* qkv_w  = (const float*)d_in[3];
  const float* proj_w = (const float*)d_in[4];
  const float* proj_b = (const float*)d_in[5];
  const int*   rpi    = (const int*)d_in[6];
  float* out = (float*)d_out;

  char* ws = (char*)d_ws;
  __bf16* qkv      = (__bf16*)(ws);                   // 16384*9408*2 = 308,281,344
  __bf16* y        = (__bf16*)(ws + 308281344);       // 200704*256*2 = 102,760,448
  __bf16* qkvw_b   = (__bf16*)(ws + 411041792);       // 393,216
  __bf16* projw_b  = (__bf16*)(ws + 411435008);       // 131,072
  float*  cmb      = (float*) (ws + 411566080);       // 256*8*98*128*4 = 102,760,448 (~514MB)

  int prep_n = 256 * 8 * NTOK * 128;
  prep_kernel<<<(prep_n + 255) / 256, 256, 0, stream>>>(qkv_w, proj_w, pbt, rpi, mask,
                                                        qkvw_b, projw_b, cmb);
  gemm_qkv<<<MROWS / 128, 512, 0, stream>>>(x, qkvw_b, qkv);
  attn_kernel<<<NWIN * 8, 128, 0, stream>>>(qkv, cmb, y);
  gemm_proj<<<(MROWS / 128) * 2, 256, 0, stream>>>(y, projw_b, proj_b, out);
}

// Round 18
// 502.741 us; speedup vs baseline: 1.1390x; 1.1390x over previous
//
#include <hip/hip_runtime.h>
#include <hip/hip_bf16.h>
#include <math.h>

typedef float f32x4 __attribute__((ext_vector_type(4)));
typedef __bf16 bf16x8 __attribute__((ext_vector_type(8)));

#define NTOK 98
#define NWIN 2048
#define NN (NTOK * NTOK)            // 9604
#define SCALE 0.17677669529663689f
#define MROWS (NWIN * NTOK)         // 200704
#define PSTRIDE 9408                // per-(win,h): q 3136 + k 3136 + v 3136 elems

// ---------------- async global->LDS 16B ----------------
__device__ __forceinline__ void g2l16(const void* g, void* l) {
  typedef __attribute__((address_space(1))) const unsigned int GU;
  typedef __attribute__((address_space(3))) unsigned int LU;
  __builtin_amdgcn_global_load_lds((GU*)g, (LU*)l, 16, 0, 0);
}

// ---------------- prep: weights->bf16, bias_pad[8][98][128], mask_pad[256][98][128] ----------------
__global__ void prep_kernel(const float* __restrict__ qkv_w, const float* __restrict__ proj_w,
                            const float* __restrict__ pbt, const int* __restrict__ rpi,
                            const float* __restrict__ mask,
                            __bf16* __restrict__ qkvw_b, __bf16* __restrict__ projw_b,
                            float* __restrict__ bias_pad, float* __restrict__ mask_pad) {
  int i = blockIdx.x * 256 + threadIdx.x;
  if (i < 768 * 256) qkvw_b[i] = (__bf16)qkv_w[i];
  if (i < 256 * 256) projw_b[i] = (__bf16)proj_w[i];
  if (i < 8 * NTOK * 128) {
    int h = i / (NTOK * 128); int r2 = i - h * (NTOK * 128);
    int row = r2 >> 7, j = r2 & 127;
    bias_pad[i] = (j < NTOK) ? pbt[rpi[row * NTOK + j] * 8 + h] : 0.f;
  }
  if (i < 256 * NTOK * 128) {
    int m = i / (NTOK * 128); int r2 = i - m * (NTOK * 128);
    int row = r2 >> 7, j = r2 & 127;
    mask_pad[i] = (j < NTOK) ? mask[m * NN + row * NTOK + j] : 0.f;
  }
}

// ---------------- QKV GEMM: A once, B dbuf BK=32, 256 thr (R16-proven) ----------------
__launch_bounds__(256)
__global__ void gemm_qkv(const float* __restrict__ A, const __bf16* __restrict__ W,
                         __bf16* __restrict__ C) {
  __shared__ __align__(16) char As[65536];       // [128 rows][256 bf16] swizzled
  __shared__ __align__(16) char Bs[2][8192];     // [128 rows][32 bf16] swizzled, dbuf
  const int m0 = blockIdx.x * 128;
  const int tid = threadIdx.x;
  const int lane = tid & 63;
  const int wid = tid >> 6;
  const int wm = wid & 1, wn = wid >> 1;
  const int lr = lane & 15;
  const int lg = lane >> 4;

  // stage A once: fp32 -> bf16 through regs, swizzled, K fully resident
  for (int c = tid; c < 128 * 32; c += 256) {
    int row = c >> 5, slot = c & 31;
    const float* ap = A + (size_t)(m0 + row) * 256 + slot * 8;
    float4 f0 = *(const float4*)ap;
    float4 f1 = *(const float4*)(ap + 4);
    bf16x8 hv;
    hv[0] = (__bf16)f0.x; hv[1] = (__bf16)f0.y; hv[2] = (__bf16)f0.z; hv[3] = (__bf16)f0.w;
    hv[4] = (__bf16)f1.x; hv[5] = (__bf16)f1.y; hv[6] = (__bf16)f1.z; hv[7] = (__bf16)f1.w;
    *(bf16x8*)(As + row * 512 + ((slot * 16) ^ ((row & 7) << 4))) = hv;
  }
  __syncthreads();

  for (int nt = 0; nt < 6; ++nt) {
    const int n0 = nt * 128;
    f32x4 acc[4][4] = {};

    // stage B k-step 0 into buf 0 (pre-swizzled source, linear dest)
#pragma unroll
    for (int it2 = 0; it2 < 2; ++it2) {
      int wc = wid * 2 + it2;
      int cc = wc * 64 + lane;
      int row = cc >> 2, slot = cc & 3;
      int sw = (row & 3) ^ ((row >> 3) & 3);
      g2l16(W + (size_t)(n0 + row) * 256 + ((slot ^ sw) * 8), (void*)(Bs[0] + wc * 1024));
    }
    __syncthreads();

    for (int ks = 0; ks < 8; ++ks) {
      const int cur = ks & 1;
      if (ks < 7) {
#pragma unroll
        for (int it2 = 0; it2 < 2; ++it2) {
          int wc = wid * 2 + it2;
          int cc = wc * 64 + lane;
          int row = cc >> 2, slot = cc & 3;
          int sw = (row & 3) ^ ((row >> 3) & 3);
          g2l16(W + (size_t)(n0 + row) * 256 + (ks + 1) * 32 + ((slot ^ sw) * 8),
                (void*)(Bs[cur ^ 1] + wc * 1024));
        }
      }
      bf16x8 a[4], b[4];
#pragma unroll
      for (int m = 0; m < 4; ++m) {
        int row = wm * 64 + m * 16 + lr;
        a[m] = *(const bf16x8*)(As + row * 512 + ((ks * 64 + lg * 16) ^ ((row & 7) << 4)));
      }
#pragma unroll
      for (int n = 0; n < 4; ++n) {
        int row = wn * 64 + n * 16 + lr;
        int sw = (row & 3) ^ ((row >> 3) & 3);
        b[n] = *(const bf16x8*)(Bs[cur] + row * 64 + ((lg * 16) ^ (sw << 4)));
      }
#pragma unroll
      for (int m = 0; m < 4; ++m)
#pragma unroll
        for (int n = 0; n < 4; ++n)
          acc[m][n] = __builtin_amdgcn_mfma_f32_16x16x32_bf16(a[m], b[n], acc[m][n], 0, 0, 0);
      __syncthreads();
    }

    // epilogue for this nt: head-blocked, linear [tok][32] -> coalesced 32B stores
#pragma unroll
    for (int m = 0; m < 4; ++m)
#pragma unroll
      for (int r = 0; r < 4; ++r) {
        unsigned row = m0 + wm * 64 + m * 16 + lg * 4 + r;
        unsigned win = row / NTOK;
        unsigned tok = row - win * NTOK;
#pragma unroll
        for (int n = 0; n < 4; ++n) {
          int col = n0 + wn * 64 + n * 16 + lr;
          int sec = col >> 8, dd = col & 255;
          int h = dd >> 5, d = dd & 31;
          C[(size_t)(win * 8 + h) * PSTRIDE + (size_t)sec * 3136 + tok * 32 + d] =
              (__bf16)acc[m][n][r];
        }
      }
  }
}

// ---------------- attention: bias(L2)+mask(L3) separate; hoisted K frags; VT in LDS ----------------
__launch_bounds__(128)
__global__ void attn_kernel(const __bf16* __restrict__ qkv, const float* __restrict__ bias_pad,
                            const float* __restrict__ mask_pad, __bf16* __restrict__ y) {
  __shared__ __align__(16) char VTB[8192];      // VT [32 d][128 j] bf16, swizzled
  int bx = blockIdx.x;
  int lb = (bx & 7) * 2048 + (bx >> 3);         // win-major within each XCD
  const int win = lb >> 3, h = lb & 7;
  const int tid = threadIdx.x;
  const int lane = tid & 63, wv = tid >> 6;
  const int lr = lane & 15, lg = lane >> 4;
  const f32x4 fz = {0.f, 0.f, 0.f, 0.f};

  const __bf16* qw = qkv + (size_t)(win * 8 + h) * PSTRIDE;
  const __bf16* kw = qw + 3136;
  const __bf16* vw = qw + 6272;                 // v [tok][32]
  const float* bb = bias_pad + h * (NTOK * 128);
  const float* mm = mask_pad + (size_t)(win & 255) * (NTOK * 128);

  // stage V transposed -> VT (clamped rows j>=98; they multiply P=0)
  for (int c = tid; c < 512; c += 128) {
    int j = c & 127; int jc = j < NTOK ? j : NTOK - 1;
    int d8 = (c >> 7) << 3;
    bf16x8 vv = *(const bf16x8*)(vw + jc * 32 + d8);
#pragma unroll
    for (int e = 0; e < 8; ++e) {
      int d = d8 + e;
      *(__bf16*)(VTB + d * 256 + ((2 * j) ^ ((d & 7) << 4))) = vv[e];
    }
  }

  // hoist K fragments (i-tile-invariant), permuted so P slots == PV A-frag slots
  bf16x8 bk[7];
#pragma unroll
  for (int jt = 0; jt < 7; ++jt) {
    int brow = ((jt >> 1) << 5) + ((lr >> 2) << 3) + ((jt & 1) << 2) + (lr & 3);
    int browc = brow < NTOK ? brow : NTOK - 1;
    bk[jt] = *(const bf16x8*)(kw + browc * 32 + lg * 8);
  }
  __syncthreads();

  for (int it = wv; it < 7; it += 2) {          // wave0: 0,2,4,6  wave1: 1,3,5
    const int i0 = it * 16;
    const int qrow = i0 + lr;
    const int qrowc = qrow < NTOK ? qrow : NTOK - 1;
    bf16x8 aq = *(const bf16x8*)(qw + qrowc * 32 + lg * 8);

    // prefetch bias (L2-hot) + mask (L3-resident), fuse to cv before MFMAs
    const float* br = bb + qrowc * 128;
    const float* mr = mm + qrowc * 128;
    float4 cv[7];
#pragma unroll
    for (int jt = 0; jt < 7; ++jt) {
      int kb = ((jt >> 1) << 5) + lg * 8 + ((jt & 1) << 2);
      float4 b4 = *(const float4*)(br + kb);
      float4 m4 = *(const float4*)(mr + kb);
      cv[jt].x = b4.x + m4.x; cv[jt].y = b4.y + m4.y;
      cv[jt].z = b4.z + m4.z; cv[jt].w = b4.w + m4.w;
    }

    // S^T = K Q^T: lane holds P[qrow][k], k = 32*(jt>>1) + lg*8 + 4*(jt&1) + r
    f32x4 s[7];
#pragma unroll
    for (int jt = 0; jt < 7; ++jt)
      s[jt] = __builtin_amdgcn_mfma_f32_16x16x32_bf16(bk[jt], aq, fz, 0, 0, 0);

    // softmax fully in-register (row qrow)
    float sv[7][4];
    float mx = -INFINITY;
#pragma unroll
    for (int jt = 0; jt < 7; ++jt) {
      int kb = ((jt >> 1) << 5) + lg * 8 + ((jt & 1) << 2);
#pragma unroll
      for (int r = 0; r < 4; ++r) {
        float xv = (kb + r < NTOK) ? fmaf(SCALE, s[jt][r], (&cv[jt].x)[r]) : -INFINITY;
        sv[jt][r] = xv;
        mx = fmaxf(mx, xv);
      }
    }
    mx = fmaxf(mx, __shfl_xor(mx, 16));
    mx = fmaxf(mx, __shfl_xor(mx, 32));
    float sum = 0.f;
#pragma unroll
    for (int jt = 0; jt < 7; ++jt)
#pragma unroll
      for (int r = 0; r < 4; ++r) {
        float p = __expf(sv[jt][r] - mx);
        sv[jt][r] = p;
        sum += p;
      }
    sum += __shfl_xor(sum, 16);
    sum += __shfl_xor(sum, 32);
    const float rinv = 1.f / sum;               // for row i0 + lr

    // PV A-frags (unnormalized); jt==7 phantom slots -> 0
    bf16x8 pa[4];
#pragma unroll
    for (int ks = 0; ks < 4; ++ks)
#pragma unroll
      for (int e = 0; e < 8; ++e) {
        int jt = 2 * ks + (e >> 2);
        pa[ks][e] = (jt < 7) ? (__bf16)sv[jt][e & 3] : (__bf16)0.f;
      }

    // output row of o[r] is i0+lg*4+r -> reciprocal from lane lg*4+r
    float rv[4];
#pragma unroll
    for (int r = 0; r < 4; ++r) rv[r] = __shfl(rinv, lg * 4 + r);

    // PV from LDS V^T; y write with row-correct reciprocal
#pragma unroll
    for (int dt = 0; dt < 2; ++dt) {
      f32x4 o = fz;
#pragma unroll
      for (int ks = 0; ks < 4; ++ks) {
        int vrow = dt * 16 + lr;
        bf16x8 vb = *(const bf16x8*)(VTB + vrow * 256 + ((ks * 64 + lg * 16) ^ ((vrow & 7) << 4)));
        o = __builtin_amdgcn_mfma_f32_16x16x32_bf16(pa[ks], vb, o, 0, 0, 0);
      }
#pragma unroll
      for (int r = 0; r < 4; ++r) {
        int row = i0 + lg * 4 + r;
        if (row < NTOK)
          y[((size_t)win * NTOK + row) * 256 + h * 32 + dt * 16 + lr] = (__bf16)(o[r] * rv[r]);
      }
    }
  }
}

// ---------------- proj GEMM: out[M][256] = y[M][256] @ W[256][256]^T + b ----------------
__launch_bounds__(256)
__global__ void gemm_proj(const __bf16* __restrict__ A, const __bf16* __restrict__ W,
                          const float* __restrict__ pb, float* __restrict__ C) {
  __shared__ __align__(16) char As[128 * 128];
  __shared__ __align__(16) char Bs[128 * 128];
  const int bid = blockIdx.x;
  const int m0 = (bid / 2) * 128;
  const int n0 = (bid % 2) * 128;
  const int tid = threadIdx.x;
  const int lane = tid & 63;
  const int wid = tid >> 6;
  const int wm = wid & 1, wn = wid >> 1;
  const int lr = lane & 15;
  const int lg = lane >> 4;
  f32x4 acc[4][4] = {};

  for (int k0 = 0; k0 < 256; k0 += 64) {
#pragma unroll
    for (int it = 0; it < 4; ++it) {
      int c = wid * 4 + it;
      int row = c * 8 + (lane >> 3);
      int src_chunk = (lane & 7) ^ (row & 7);
      g2l16(A + (size_t)(m0 + row) * 256 + k0 + src_chunk * 8, (void*)(As + c * 1024));
      g2l16(W + (size_t)(n0 + row) * 256 + k0 + src_chunk * 8, (void*)(Bs + c * 1024));
    }
    __syncthreads();
#pragma unroll
    for (int kk = 0; kk < 2; ++kk) {
      bf16x8 a[4], b[4];
#pragma unroll
      for (int m = 0; m < 4; ++m) {
        int row = wm * 64 + m * 16 + lr;
        a[m] = *(const bf16x8*)(As + row * 128 + ((kk * 64 + lg * 16) ^ ((row & 7) << 4)));
      }
#pragma unroll
      for (int n = 0; n < 4; ++n) {
        int row = wn * 64 + n * 16 + lr;
        b[n] = *(const bf16x8*)(Bs + row * 128 + ((kk * 64 + lg * 16) ^ ((row & 7) << 4)));
      }
#pragma unroll
      for (int m = 0; m < 4; ++m)
#pragma unroll
        for (int n = 0; n < 4; ++n)
          acc[m][n] = __builtin_amdgcn_mfma_f32_16x16x32_bf16(a[m], b[n], acc[m][n], 0, 0, 0);
    }
    __syncthreads();
  }
#pragma unroll
  for (int m = 0; m < 4; ++m) {
    int row = m0 + wm * 64 + m * 16 + lg * 4;
#pragma unroll
    for (int n = 0; n < 4; ++n) {
      int col = n0 + wn * 64 + n * 16 + lr;
      float bv = pb[col];
#pragma unroll
      for (int r = 0; r < 4; ++r)
        C[(size_t)(row + r) * 256 + col] = acc[m][n][r] + bv;
    }
  }
}

// ---------------- launch ----------------
extern "C" void kernel_launch(void* const* d_in, const int* in_sizes, int n_in,
                              void* d_out, int out_size, void* d_ws, size_t ws_size,
                              hipStream_t stream) {
  const float* x      = (const float*)d_in[0];
  const float* mask   = (const float*)d_in[1];
  const float* pbt    = (const float*)d_in[2];
  const float* qkv_w  = (const float*)d_in[3];
  const float* proj_w = (const float*)d_in[4];
  const float* proj_b = (const float*)d_in[5];
  const int*   rpi    = (const int*)d_in[6];
  float* out = (float*)d_out;

  char* ws = (char*)d_ws;
  __bf16* qkv      = (__bf16*)(ws);                   // 16384*9408*2 = 308,281,344
  __bf16* y        = (__bf16*)(ws + 308281344);       // 200704*256*2 = 102,760,448
  __bf16* qkvw_b   = (__bf16*)(ws + 411041792);       // 393,216
  __bf16* projw_b  = (__bf16*)(ws + 411435008);       // 131,072
  float*  bias_pad = (float*) (ws + 411566080);       // 401,408
  float*  mask_pad = (float*) (ws + 411967488);       // 12,845,056  (~425MB total)

  int prep_n = 256 * NTOK * 128;
  prep_kernel<<<(prep_n + 255) / 256, 256, 0, stream>>>(qkv_w, proj_w, pbt, rpi, mask,
                                                        qkvw_b, projw_b, bias_pad, mask_pad);
  gemm_qkv<<<MROWS / 128, 256, 0, stream>>>(x, qkvw_b, qkv);
  attn_kernel<<<NWIN * 8, 128, 0, stream>>>(qkv, bias_pad, mask_pad, y);
  gemm_proj<<<(MROWS / 128) * 2, 256, 0, stream>>>(y, projw_b, proj_b, out);
}